// Round 7
// baseline (257.497 us; speedup 1.0000x reference)
//
#include <hip/hip_runtime.h>

#define LOG2E 1.4426950408889634f

// Problem constants
constexpr int Bb = 4, LQ = 512, LK = 512, QS = 512, H = 256, DV = 512;
constexpr int M = Bb * LQ;   // 2048 rows for each projection input

// Workspace layout (floats):
//  [0 .. 1M)       ATq  [512][2048]   (later aliased by ScT — dead after proj)
//  [1M .. 2M)      ATk  [512][2048]
//  [0 .. 1M)       ScT  [B][LK][LQ]   (alias of ATq/ATk region, written later)
//  [2M .. )        WTq  [512][256]
//  ...             WTk, Wv2, EqT, EkT, rowpart
constexpr size_t OFF_AT   = 0;                       // 2 x 1048576
constexpr size_t OFF_SCT  = 0;                       // 1048576 (alias, used after proj)
constexpr size_t OFF_WT   = 2097152;                 // 2 x 131072
constexpr size_t OFF_WV2  = 2359296;                 // 256 (pad to 2359552)
constexpr size_t OFF_EQT  = 2359552;                 // 524288
constexpr size_t OFF_EKT  = 2883840;                 // 524288
constexpr size_t OFF_ROW  = 3408128;                 // 8 x 2048

// ---------------------------------------------------------------------------
// Kernel T: transpose to k-major.  z=0: query->ATq, z=1: key->ATk,
// z=2: wq->WTq (+ one block fills Wv2 = wv*2log2e), z=3: wk->WTk.
// 64x64 LDS tiles, pitch 65 (conflict-free), float4 both phases.
// ---------------------------------------------------------------------------
__global__ __launch_bounds__(256) void transpose_kernel(
    const float* __restrict__ query, const float* __restrict__ key,
    const float* __restrict__ wq,    const float* __restrict__ wk,
    const float* __restrict__ wv,    float* __restrict__ ws)
{
    const int z = blockIdx.z;
    const int C = 512;
    const int R = (z < 2) ? 2048 : 256;
    const float* src = (z == 0) ? query : (z == 1) ? key : (z == 2) ? wq : wk;
    float* dst = (z == 0) ? ws + OFF_AT
               : (z == 1) ? ws + OFF_AT + 1048576
               : (z == 2) ? ws + OFF_WT
               :            ws + OFF_WT + 131072;

    const int tid = threadIdx.x;

    // side duty: one otherwise-idle W block scales wv into Wv2
    if (z == 2 && blockIdx.x == 31 && blockIdx.y == 0) {
        ws[OFF_WV2 + tid] = wv[tid] * (2.0f * LOG2E);
        return;
    }
    if (z >= 2 && blockIdx.x >= 4) return;

    __shared__ float T[64][65];
    const int rb = blockIdx.x * 64;
    const int cb = blockIdx.y * 64;
    const int tx = tid & 15, ty = tid >> 4;   // ty 0..15

    // load 64x64 tile: thread handles rows ty+16i, cols tx*4..+3
#pragma unroll
    for (int i = 0; i < 4; ++i) {
        float4 v = *(const float4*)(src + (size_t)(rb + ty + 16 * i) * C + cb + tx * 4);
        T[ty + 16 * i][tx * 4 + 0] = v.x;
        T[ty + 16 * i][tx * 4 + 1] = v.y;
        T[ty + 16 * i][tx * 4 + 2] = v.z;
        T[ty + 16 * i][tx * 4 + 3] = v.w;
    }
    __syncthreads();
    // store transposed: out[cb+c][rb + tx*4 .. +3] = T[tx*4..+3][c]
#pragma unroll
    for (int j = 0; j < 4; ++j) {
        int c = ty + 16 * j;
        float4 o;
        o.x = T[tx * 4 + 0][c];
        o.y = T[tx * 4 + 1][c];
        o.z = T[tx * 4 + 2][c];
        o.w = T[tx * 4 + 3][c];
        *(float4*)(dst + (size_t)(cb + c) * R + rb + tx * 4) = o;
    }
}

// ---------------------------------------------------------------------------
// Kernel A: projection, lane-major, LDS-free inner loop.
//   EqT[n][m] = exp2( clamp( scale*(sum_k AT[k][m]*WT[k][n] + bias[n]), ±30 ) )
// lane l -> m = mb+l (coalesced b32 A-loads); wave -> 16 n via wave-uniform
// 64B loads (s_load into SGPRs, scalar fma operand).  Grid (32,4,2)=256 blk.
// ---------------------------------------------------------------------------
__global__ __launch_bounds__(256) void proj_kernel(
    const float* __restrict__ Bq, const float* __restrict__ Bk,
    float* __restrict__ ws, float scale)
{
    const int z = blockIdx.z;
    const float* AT   = ws + OFF_AT + (size_t)z * 1048576;   // [512][2048]
    const float* WT   = ws + OFF_WT + (size_t)z * 131072;    // [512][256]
    const float* bias = z ? Bk : Bq;
    float*       out  = ws + ((z == 0) ? OFF_EQT : OFF_EKT); // [256][2048]

    const int mb = blockIdx.x * 64;
    const int ny = blockIdx.y * 64;
    const int tid = threadIdx.x;
    const int l = tid & 63;
    const int w = __builtin_amdgcn_readfirstlane(tid >> 6);
    const int nset = ny + w * 16;

    float acc[16] = {};
    const float* ap = AT + mb + l;
    const float4* wp = (const float4*)(WT + nset);   // row stride 64 float4s

#pragma unroll 4
    for (int k = 0; k < QS; ++k) {
        float at = ap[(size_t)k * 2048];
        float4 w0 = wp[(size_t)k * 64 + 0];
        float4 w1 = wp[(size_t)k * 64 + 1];
        float4 w2 = wp[(size_t)k * 64 + 2];
        float4 w3 = wp[(size_t)k * 64 + 3];
        acc[0]  = fmaf(at, w0.x, acc[0]);
        acc[1]  = fmaf(at, w0.y, acc[1]);
        acc[2]  = fmaf(at, w0.z, acc[2]);
        acc[3]  = fmaf(at, w0.w, acc[3]);
        acc[4]  = fmaf(at, w1.x, acc[4]);
        acc[5]  = fmaf(at, w1.y, acc[5]);
        acc[6]  = fmaf(at, w1.z, acc[6]);
        acc[7]  = fmaf(at, w1.w, acc[7]);
        acc[8]  = fmaf(at, w2.x, acc[8]);
        acc[9]  = fmaf(at, w2.y, acc[9]);
        acc[10] = fmaf(at, w2.z, acc[10]);
        acc[11] = fmaf(at, w2.w, acc[11]);
        acc[12] = fmaf(at, w3.x, acc[12]);
        acc[13] = fmaf(at, w3.y, acc[13]);
        acc[14] = fmaf(at, w3.z, acc[14]);
        acc[15] = fmaf(at, w3.w, acc[15]);
    }
#pragma unroll
    for (int j = 0; j < 16; ++j) {
        int n = nset + j;
        float v = scale * (acc[j] + bias[n]);
        v = fminf(fmaxf(v, -30.f), 30.f);
        out[(size_t)n * 2048 + mb + l] = __builtin_amdgcn_exp2f(v);
    }
}

// ---------------------------------------------------------------------------
// Kernel B: scores -> P = exp2(-acc) + per-(ktile) row partial sums.
//   acc(q,k) = sum_h Wv2[h]/(1 + Eq[h][q]*Ek[h][k]),  h-terms PAIRED
//   (one rcp per two h).  lane l -> q = qb+l (coalesced b32 Eq loads);
//   wave -> 16 k wave-uniform (SGPR Ek).  No LDS in the h-loop, no barrier.
//   Grid (8,8,4) = 256 blocks.
// ---------------------------------------------------------------------------
__global__ __launch_bounds__(256) void score_kernel(float* __restrict__ ws)
{
    const float* EqT = ws + OFF_EQT;   // [256][2048]
    const float* EkT = ws + OFF_EKT;
    const float* Wv2 = ws + OFF_WV2;
    float* ScT = ws + OFF_SCT;         // [B][LK][LQ]
    float* rowpart = ws + OFF_ROW;     // [8][2048]

    const int b  = blockIdx.z;
    const int qb = blockIdx.x * 64;
    const int kt = blockIdx.y;
    const int kb = kt * 64;
    const int tid = threadIdx.x;
    const int l = tid & 63;
    const int w = __builtin_amdgcn_readfirstlane(tid >> 6);

    const float* eqp = EqT + b * 512 + qb + l;            // + h*2048
    const float4* ekp = (const float4*)(EkT + b * 512 + kb + w * 16); // + h*512 f4

    float acc[16] = {};

#pragma unroll 2
    for (int h = 0; h < H; h += 2) {
        float eq1 = eqp[(size_t)h * 2048];
        float eq2 = eqp[(size_t)(h + 1) * 2048];
        float4 e1a = ekp[(size_t)h * 512 + 0];
        float4 e1b = ekp[(size_t)h * 512 + 1];
        float4 e1c = ekp[(size_t)h * 512 + 2];
        float4 e1d = ekp[(size_t)h * 512 + 3];
        float4 e2a = ekp[(size_t)(h + 1) * 512 + 0];
        float4 e2b = ekp[(size_t)(h + 1) * 512 + 1];
        float4 e2c = ekp[(size_t)(h + 1) * 512 + 2];
        float4 e2d = ekp[(size_t)(h + 1) * 512 + 3];
        float w1 = Wv2[h];
        float w2 = Wv2[h + 1];
        const float e1[16] = {e1a.x, e1a.y, e1a.z, e1a.w, e1b.x, e1b.y, e1b.z, e1b.w,
                              e1c.x, e1c.y, e1c.z, e1c.w, e1d.x, e1d.y, e1d.z, e1d.w};
        const float e2[16] = {e2a.x, e2a.y, e2a.z, e2a.w, e2b.x, e2b.y, e2b.z, e2b.w,
                              e2c.x, e2c.y, e2c.z, e2c.w, e2d.x, e2d.y, e2d.z, e2d.w};
#pragma unroll
        for (int j = 0; j < 16; ++j) {
            float ta = fmaf(eq1, e1[j], 1.0f);
            float tb = fmaf(eq2, e2[j], 1.0f);
            float num = fmaf(w1, tb, w2 * ta);
            acc[j] = fmaf(num, __builtin_amdgcn_rcpf(ta * tb), acc[j]);
        }
    }

    // Epilogue: P stores (coalesced b32 per k-row) + wave partial row sums.
    float s = 0.f;
#pragma unroll
    for (int j = 0; j < 16; ++j) {
        float p = __builtin_amdgcn_exp2f(-acc[j]);
        s += p;
        ScT[((size_t)b * 512 + kb + w * 16 + j) * 512 + qb + l] = p;
    }
    __shared__ float red[4][64];
    red[w][l] = s;
    __syncthreads();
    if (tid < 64) {
        float t = ((red[0][tid] + red[1][tid]) + (red[2][tid] + red[3][tid]));
        rowpart[(size_t)kt * 2048 + b * 512 + qb + tid] = t;
    }
}

// ---------------------------------------------------------------------------
// Kernel C: out = (P @ V) / rowsum.  lane l -> q = qb+l (coalesced b32 P
// loads); wave -> 16 n wave-uniform (SGPR V).  LDS-free, barrier-free.
// Grid (8,8,4) = 256 blocks.
// ---------------------------------------------------------------------------
__global__ __launch_bounds__(256) void av_kernel(
    const float* __restrict__ V,    // [B][LK][DV]
    const float* __restrict__ ws_c,
    float* __restrict__ O)          // [B][LQ][DV]
{
    const float* ScT = ws_c + OFF_SCT;
    const float* rowpart = ws_c + OFF_ROW;

    const int b  = blockIdx.z;
    const int qb = blockIdx.x * 64;
    const int nb = blockIdx.y * 64;
    const int tid = threadIdx.x;
    const int l = tid & 63;
    const int w = __builtin_amdgcn_readfirstlane(tid >> 6);
    const int nset = nb + w * 16;

    const float* pp = ScT + (size_t)b * 512 * 512 + qb + l;       // + k*512
    const float4* vp = (const float4*)(V + (size_t)b * 512 * 512 + nset);

    float acc[16] = {};

#pragma unroll 4
    for (int k = 0; k < LK; ++k) {
        float p = pp[(size_t)k * 512];
        float4 v0 = vp[(size_t)k * 128 + 0];
        float4 v1 = vp[(size_t)k * 128 + 1];
        float4 v2 = vp[(size_t)k * 128 + 2];
        float4 v3 = vp[(size_t)k * 128 + 3];
        acc[0]  = fmaf(p, v0.x, acc[0]);
        acc[1]  = fmaf(p, v0.y, acc[1]);
        acc[2]  = fmaf(p, v0.z, acc[2]);
        acc[3]  = fmaf(p, v0.w, acc[3]);
        acc[4]  = fmaf(p, v1.x, acc[4]);
        acc[5]  = fmaf(p, v1.y, acc[5]);
        acc[6]  = fmaf(p, v1.z, acc[6]);
        acc[7]  = fmaf(p, v1.w, acc[7]);
        acc[8]  = fmaf(p, v2.x, acc[8]);
        acc[9]  = fmaf(p, v2.y, acc[9]);
        acc[10] = fmaf(p, v2.z, acc[10]);
        acc[11] = fmaf(p, v2.w, acc[11]);
        acc[12] = fmaf(p, v3.x, acc[12]);
        acc[13] = fmaf(p, v3.y, acc[13]);
        acc[14] = fmaf(p, v3.z, acc[14]);
        acc[15] = fmaf(p, v3.w, acc[15]);
    }

    // row sum over the 8 k-tiles
    float rs = 0.f;
#pragma unroll
    for (int t = 0; t < 8; ++t)
        rs += rowpart[(size_t)t * 2048 + b * 512 + qb + l];
    float rr = 1.0f / rs;

    float* op = O + ((size_t)b * 512 + qb + l) * 512 + nset;
#pragma unroll
    for (int g = 0; g < 4; ++g) {
        float4 o;
        o.x = acc[g * 4 + 0] * rr;
        o.y = acc[g * 4 + 1] * rr;
        o.z = acc[g * 4 + 2] * rr;
        o.w = acc[g * 4 + 3] * rr;
        *(float4*)(op + g * 4) = o;
    }
}

extern "C" void kernel_launch(void* const* d_in, const int* in_sizes, int n_in,
                              void* d_out, int out_size, void* d_ws, size_t ws_size,
                              hipStream_t stream) {
    const float* query = (const float*)d_in[0];
    const float* key   = (const float*)d_in[1];
    const float* value = (const float*)d_in[2];
    const float* wq    = (const float*)d_in[3];
    const float* bq    = (const float*)d_in[4];
    const float* wk    = (const float*)d_in[5];
    const float* bk    = (const float*)d_in[6];
    const float* wv    = (const float*)d_in[7];
    // d_in[8] = bv: row-constant -> softmax-invariant, dropped.
    float* out = (float*)d_out;
    float* ws  = (float*)d_ws;

    const float c2 = 2.0f * LOG2E;

    transpose_kernel<<<dim3(32, 8, 4), 256, 0, stream>>>(query, key, wq, wk, wv, ws);
    proj_kernel<<<dim3(32, 4, 2), 256, 0, stream>>>(bq, bk, ws, c2);
    score_kernel<<<dim3(8, 8, Bb), 256, 0, stream>>>(ws);
    av_kernel<<<dim3(8, 8, Bb), 256, 0, stream>>>(value, ws, out);
}

// Round 8
// 177.695 us; speedup vs baseline: 1.4491x; 1.4491x over previous
//
#include <hip/hip_runtime.h>

#define LOG2E 1.4426950408889634f

// Problem constants
constexpr int Bb = 4, LQ = 512, LK = 512, QS = 512, H = 256, DV = 512;
constexpr int M = Bb * LQ;   // 2048

// Workspace layout (float offsets)
constexpr size_t OFF_WT  = 0;          // 2 x [512][256] k-major weights
constexpr size_t OFF_WV2 = 262144;     // [256] wv * 2log2e
constexpr size_t OFF_EQT = 262400;     // [256][2048] exp2-domain q proj
constexpr size_t OFF_EKT = 786688;     // [256][2048]
constexpr size_t OFF_SCT = 1310976;    // [4][512][512] P values (k-major)
constexpr size_t OFF_ROW = 2359552;    // [8][2048] rowsum partials

// ---------------------------------------------------------------------------
// Kernel T: transpose wq/wk ([256][512] -> [512][256] k-major).  Tiny: 512KB.
// z=0: wq (block (0,0) also fills Wv2), z=1: wk.  64x64 LDS tile, pitch 65.
// ---------------------------------------------------------------------------
__global__ __launch_bounds__(256) void transw_kernel(
    const float* __restrict__ wq, const float* __restrict__ wk,
    const float* __restrict__ wv, float* __restrict__ ws)
{
    const int z = blockIdx.z;
    const float* src = z ? wk : wq;            // [256][512]
    float* dst = ws + OFF_WT + (size_t)z * 131072;  // [512][256]
    const int tid = threadIdx.x;

    if (z == 0 && blockIdx.x == 0 && blockIdx.y == 0)
        ws[OFF_WV2 + tid] = wv[tid] * (2.0f * LOG2E);

    __shared__ float T[64][65];
    const int rb = blockIdx.x * 64;    // src row block (0..3)
    const int cb = blockIdx.y * 64;    // src col block (0..7)
    const int tx = tid & 15, ty = tid >> 4;

#pragma unroll
    for (int i = 0; i < 4; ++i) {
        float4 v = *(const float4*)(src + (size_t)(rb + ty + 16 * i) * 512 + cb + tx * 4);
        T[ty + 16 * i][tx * 4 + 0] = v.x;
        T[ty + 16 * i][tx * 4 + 1] = v.y;
        T[ty + 16 * i][tx * 4 + 2] = v.z;
        T[ty + 16 * i][tx * 4 + 3] = v.w;
    }
    __syncthreads();
#pragma unroll
    for (int j = 0; j < 4; ++j) {
        int c = ty + 16 * j;
        float4 o;
        o.x = T[tx * 4 + 0][c];
        o.y = T[tx * 4 + 1][c];
        o.z = T[tx * 4 + 2][c];
        o.w = T[tx * 4 + 3][c];
        *(float4*)(dst + (size_t)(cb + c) * 256 + rb + tx * 4) = o;
    }
}

// ---------------------------------------------------------------------------
// Kernel A: projection + exp2 epilogue.
//   EqT[n][m] = exp2( clamp( scale*(A[m]·W[n] + bias[n]), ±30 ) )
// A-tile transposed in LDS to k-major chunks At[128][65] (pad-65: scatter
// writes and b128 frag reads both conflict-free).  W streamed from global
// (k-major WT) as per-k b128 vector loads — no LDS for B, 8 barriers total.
// 64m x 64n tile, 4x4/thread.  Grid (32,4,2) = 256 blocks, 256 thr.
// ---------------------------------------------------------------------------
__global__ __launch_bounds__(256) void proj_kernel(
    const float* __restrict__ query, const float* __restrict__ key,
    const float* __restrict__ Bq, const float* __restrict__ Bk,
    float* __restrict__ ws, float scale)
{
    const int z = blockIdx.z;
    const float* A    = z ? key : query;                   // [2048][512]
    const float* WT   = ws + OFF_WT + (size_t)z * 131072;  // [512][256]
    const float* bias = z ? Bk : Bq;
    float*       out  = ws + (z ? OFF_EKT : OFF_EQT);      // [256][2048]

    __shared__ float At[128][65];    // [k][m] chunk
    const int mb = blockIdx.x * 64;
    const int nb = blockIdx.y * 64;
    const int tid = threadIdx.x;
    const int tx = tid & 15;         // m frag: tx*4 + i
    const int ty = tid >> 4;         // n frag: ty*4 + j

    float acc[4][4] = {};

    for (int k0 = 0; k0 < QS; k0 += 128) {
        __syncthreads();
        // stage: coalesced float4 row reads, scatter to k-major LDS
#pragma unroll
        for (int a = 0; a < 4; ++a) {
            int m = ty + 16 * a;
#pragma unroll
            for (int cc = 0; cc < 2; ++cc) {
                int c = cc * 64 + tx * 4;
                float4 v = *(const float4*)(A + (size_t)(mb + m) * 512 + k0 + c);
                At[c + 0][m] = v.x;
                At[c + 1][m] = v.y;
                At[c + 2][m] = v.z;
                At[c + 3][m] = v.w;
            }
        }
        __syncthreads();
        const float* wp = WT + (size_t)k0 * 256 + nb + ty * 4;
#pragma unroll 8
        for (int k = 0; k < 128; ++k) {
            float4 w4 = *(const float4*)(wp + (size_t)k * 256);
            float4 a4 = *(const float4*)&At[k][tx * 4];
            const float aa[4] = {a4.x, a4.y, a4.z, a4.w};
            const float ww[4] = {w4.x, w4.y, w4.z, w4.w};
#pragma unroll
            for (int i = 0; i < 4; ++i)
#pragma unroll
                for (int j = 0; j < 4; ++j)
                    acc[i][j] = fmaf(aa[i], ww[j], acc[i][j]);
        }
    }
    // Epilogue: bias, scale, clamp, exp2; out[n][mb+tx*4..+3] float4.
#pragma unroll
    for (int j = 0; j < 4; ++j) {
        int n = nb + ty * 4 + j;
        float bs = bias[n];
        float4 o;
        float v0 = scale * (acc[0][j] + bs);
        float v1 = scale * (acc[1][j] + bs);
        float v2 = scale * (acc[2][j] + bs);
        float v3 = scale * (acc[3][j] + bs);
        v0 = fminf(fmaxf(v0, -30.f), 30.f);
        v1 = fminf(fmaxf(v1, -30.f), 30.f);
        v2 = fminf(fmaxf(v2, -30.f), 30.f);
        v3 = fminf(fmaxf(v3, -30.f), 30.f);
        o.x = __builtin_amdgcn_exp2f(v0);
        o.y = __builtin_amdgcn_exp2f(v1);
        o.z = __builtin_amdgcn_exp2f(v2);
        o.w = __builtin_amdgcn_exp2f(v3);
        *(float4*)(out + (size_t)n * M + mb + tx * 4) = o;
    }
}

// ---------------------------------------------------------------------------
// Kernel B: scores -> P = exp2(-acc) + per-ktile row partial sums.
//   acc(q,k) = sum_h Wv2[h]/(1 + Eq[h][q]*Ek[h][k]),  h-terms paired
//   (one rcp per two h; rcp is the saturated quarter-rate pipe).
// Eq/Ek slabs LDS-resident in h-chunks of 64 -> 32 paired steps of pure
// math between barriers (8 barriers total).  64q x 64k, 4x4/thread.
// Rowsum partials via shfl butterfly + 1KB LDS.  Grid (8,8,4).
// ---------------------------------------------------------------------------
__global__ __launch_bounds__(256) void score_kernel(float* __restrict__ ws)
{
    const float* EqT = ws + OFF_EQT;   // [256][2048]
    const float* EkT = ws + OFF_EKT;
    const float* Wv2 = ws + OFF_WV2;
    float* ScT = ws + OFF_SCT;         // [4][512][512]
    float* rowpart = ws + OFF_ROW;     // [8][2048]

    __shared__ float Qs[64][64];
    __shared__ float Ks[64][64];
    __shared__ float redS[4][64];

    const int b  = blockIdx.z;
    const int qb = blockIdx.x * 64;
    const int kt = blockIdx.y;
    const int kb = kt * 64;
    const int tid = threadIdx.x;
    const int tx = tid & 15;       // q frag: tx*4 + i
    const int ty = tid >> 4;       // k frag: ty*4 + j
    const int w  = tid >> 6;       // wave id
    const int lane = tid & 63;

    const int mq = b * LQ + qb;
    const int mk = b * LK + kb;
    const int sh = tid >> 4;       // staging row 0..15 (+16,+32,+48)
    const int sm = (tid & 15) * 4; // staging col

    float acc[4][4] = {};

    for (int h0 = 0; h0 < H; h0 += 64) {
        __syncthreads();
#pragma unroll
        for (int it = 0; it < 4; ++it) {
            int h = sh + 16 * it;
            *(float4*)&Qs[h][sm] = *(const float4*)(EqT + (size_t)(h0 + h) * M + mq + sm);
            *(float4*)&Ks[h][sm] = *(const float4*)(EkT + (size_t)(h0 + h) * M + mk + sm);
        }
        __syncthreads();
#pragma unroll 4
        for (int hh = 0; hh < 64; hh += 2) {
            float4 q1 = *(const float4*)&Qs[hh][tx * 4];
            float4 q2 = *(const float4*)&Qs[hh + 1][tx * 4];
            float4 k1 = *(const float4*)&Ks[hh][ty * 4];
            float4 k2 = *(const float4*)&Ks[hh + 1][ty * 4];
            float w1 = Wv2[h0 + hh];
            float w2 = Wv2[h0 + hh + 1];
            const float q1a[4] = {q1.x, q1.y, q1.z, q1.w};
            const float q2a[4] = {q2.x, q2.y, q2.z, q2.w};
            const float k1a[4] = {k1.x, k1.y, k1.z, k1.w};
            const float k2a[4] = {k2.x, k2.y, k2.z, k2.w};
#pragma unroll
            for (int i = 0; i < 4; ++i)
#pragma unroll
                for (int j = 0; j < 4; ++j) {
                    float ta = fmaf(q1a[i], k1a[j], 1.0f);
                    float tb = fmaf(q2a[i], k2a[j], 1.0f);
                    float num = fmaf(w1, tb, w2 * ta);
                    acc[i][j] = fmaf(num, __builtin_amdgcn_rcpf(ta * tb), acc[i][j]);
                }
        }
    }

    // Epilogue: P = exp2(-acc), store k-major; row partials per q.
    float ps[4] = {0.f, 0.f, 0.f, 0.f};
#pragma unroll
    for (int j = 0; j < 4; ++j) {
        int k = kb + ty * 4 + j;
        float4 o;
        o.x = __builtin_amdgcn_exp2f(-acc[0][j]); ps[0] += o.x;
        o.y = __builtin_amdgcn_exp2f(-acc[1][j]); ps[1] += o.y;
        o.z = __builtin_amdgcn_exp2f(-acc[2][j]); ps[2] += o.z;
        o.w = __builtin_amdgcn_exp2f(-acc[3][j]); ps[3] += o.w;
        *(float4*)(ScT + ((size_t)b * 512 + k) * 512 + qb + tx * 4) = o;
    }
    // intra-wave reduce over the 4 ty-slices this wave holds
#pragma unroll
    for (int i = 0; i < 4; ++i) {
        ps[i] += __shfl_xor(ps[i], 16, 64);
        ps[i] += __shfl_xor(ps[i], 32, 64);
    }
    if (lane < 16) {
#pragma unroll
        for (int i = 0; i < 4; ++i) redS[w][tx * 4 + i] = ps[i];
    }
    __syncthreads();
    if (tid < 64) {
        float s = (redS[0][tid] + redS[1][tid]) + (redS[2][tid] + redS[3][tid]);
        rowpart[(size_t)kt * 2048 + b * 512 + qb + tid] = s;
    }
}

// ---------------------------------------------------------------------------
// Kernel C: out = (P @ V) / rowsum.
// V-slab LDS-resident in k-chunks Vs[128][64] (naturally k-major, contiguous
// coalesced staging); P streamed from global per-k b128 (256B/wave).
// 64q x 64n, 4x4/thread, 8 barriers.  Grid (8,8,4).
// ---------------------------------------------------------------------------
__global__ __launch_bounds__(256) void av_kernel(
    const float* __restrict__ V,    // [B][LK][DV]
    const float* __restrict__ ws_c,
    float* __restrict__ O)          // [B][LQ][DV]
{
    const float* ScT = ws_c + OFF_SCT;
    const float* rowpart = ws_c + OFF_ROW;

    __shared__ float Vs[128][64];
    const int b  = blockIdx.z;
    const int qb = blockIdx.x * 64;
    const int nb = blockIdx.y * 64;
    const int tid = threadIdx.x;
    const int tx = tid & 15;        // q frag: tx*4 + i
    const int ty = tid >> 4;        // n frag: ty*4 + j
    const float* S  = ScT + (size_t)b * 512 * 512;
    const float* Vb = V + (size_t)b * 512 * 512;

    const int sk = tid >> 4;        // staging k row (+16 steps)
    const int sn = (tid & 15) * 4;
    float acc[4][4] = {};

    for (int k0 = 0; k0 < LK; k0 += 128) {
        __syncthreads();
#pragma unroll
        for (int it = 0; it < 8; ++it) {
            int k = sk + 16 * it;
            *(float4*)&Vs[k][sn] = *(const float4*)(Vb + (size_t)(k0 + k) * DV + nb + sn);
        }
        __syncthreads();
        const float* pp = S + (size_t)k0 * 512 + qb + tx * 4;
#pragma unroll 8
        for (int k = 0; k < 128; ++k) {
            float4 p4 = *(const float4*)(pp + (size_t)k * 512);
            float4 v4 = *(const float4*)&Vs[k][ty * 4];
            const float pa[4] = {p4.x, p4.y, p4.z, p4.w};
            const float va[4] = {v4.x, v4.y, v4.z, v4.w};
#pragma unroll
            for (int i = 0; i < 4; ++i)
#pragma unroll
                for (int j = 0; j < 4; ++j)
                    acc[i][j] = fmaf(pa[i], va[j], acc[i][j]);
        }
    }

    // rowsum from the 8 k-tile partials
#pragma unroll
    for (int i = 0; i < 4; ++i) {
        int q = qb + tx * 4 + i;
        float rs = 0.f;
#pragma unroll
        for (int t = 0; t < 8; ++t)
            rs += rowpart[(size_t)t * 2048 + b * 512 + q];
        float rr = 1.0f / rs;
        float4 o;
        o.x = acc[i][0] * rr;
        o.y = acc[i][1] * rr;
        o.z = acc[i][2] * rr;
        o.w = acc[i][3] * rr;
        *(float4*)(O + ((size_t)b * 512 + q) * 512 + nb + ty * 4) = o;
    }
}

extern "C" void kernel_launch(void* const* d_in, const int* in_sizes, int n_in,
                              void* d_out, int out_size, void* d_ws, size_t ws_size,
                              hipStream_t stream) {
    const float* query = (const float*)d_in[0];
    const float* key   = (const float*)d_in[1];
    const float* value = (const float*)d_in[2];
    const float* wq    = (const float*)d_in[3];
    const float* bq    = (const float*)d_in[4];
    const float* wk    = (const float*)d_in[5];
    const float* bk    = (const float*)d_in[6];
    const float* wv    = (const float*)d_in[7];
    // d_in[8] = bv: row-constant -> softmax-invariant, dropped.
    float* out = (float*)d_out;
    float* ws  = (float*)d_ws;

    const float c2 = 2.0f * LOG2E;

    transw_kernel<<<dim3(4, 8, 2), 256, 0, stream>>>(wq, wk, wv, ws);
    proj_kernel<<<dim3(32, 4, 2), 256, 0, stream>>>(query, key, bq, bk, ws, c2);
    score_kernel<<<dim3(8, 8, Bb), 256, 0, stream>>>(ws);
    av_kernel<<<dim3(8, 8, Bb), 256, 0, stream>>>(value, ws, out);
}

// Round 9
// 140.338 us; speedup vs baseline: 1.8348x; 1.2662x over previous
//
#include <hip/hip_runtime.h>

#define LOG2E 1.4426950408889634f

// Problem constants
constexpr int Bb = 4, LQ = 512, LK = 512, QS = 512, H = 256, DV = 512;
constexpr int M = 2048;   // B*LQ

// Workspace byte offsets
constexpr size_t OFF_EQT = 0;            // [256][2048] f32 (2 MiB) exp2-domain q proj
constexpr size_t OFF_EKT = 2u << 20;     // [256][2048] f32 (2 MiB)
constexpr size_t OFF_PQ  = 4u << 20;     // [4][512][512] bf16 (2 MiB) P numerators
constexpr size_t OFF_ROW = 6u << 20;     // [8][2048] f32 rowsum partials

using bf16x8 = __attribute__((ext_vector_type(8))) short;
using f32x4v = __attribute__((ext_vector_type(4))) float;

__device__ inline unsigned short f2bf(float x) {
    unsigned int u = __float_as_uint(x);
    u += 0x7FFFu + ((u >> 16) & 1u);      // round-to-nearest-even
    return (unsigned short)(u >> 16);
}
__device__ inline unsigned int pk2(float lo, float hi) {
    return (unsigned int)f2bf(lo) | ((unsigned int)f2bf(hi) << 16);
}

// ---------------------------------------------------------------------------
// Kernel A: proj via bf16 MFMA + exp2 epilogue, transposed fp32 output.
//   EqT[n][m] = exp2( clamp( scale*(A[m]·W[n] + bias[n]), ±30 ) )
// A (query/key) and W are B^T-style [row][k] — MFMA's favorite layout:
// a-frag = A[m=lane&15][k=quad*8+j], b-frag = W[n=lane&15][k=quad*8+j],
// D: row(m)=quad*4+r, col(n)=lane&15 (m89-verified mapping).
// fp32->bf16 cast happens during LDS staging (no prep kernel).
// LDS pitch 136 ushort (272 B = 68 dwords ≡ 4 banks: 2-way, free).
// 64m x 64n tile, K-chunks 128, wave w owns m-strip w*16. Grid (32,4,2).
// ---------------------------------------------------------------------------
__global__ __launch_bounds__(256) void proj_mfma(
    const float* __restrict__ query, const float* __restrict__ key,
    const float* __restrict__ wq, const float* __restrict__ wk,
    const float* __restrict__ bq, const float* __restrict__ bk,
    char* __restrict__ ws, float scale)
{
    const int z = blockIdx.z;
    const float* A    = z ? key : query;   // [2048][512]
    const float* W    = z ? wk : wq;       // [256][512]
    const float* bias = z ? bk : bq;
    float* out = (float*)(ws + (z ? OFF_EKT : OFF_EQT));   // [256][2048]

    __shared__ unsigned short Als[64][136];
    __shared__ unsigned short Wls[64][136];
    __shared__ float Ot[64][68];

    const int mb = blockIdx.x * 64, nb = blockIdx.y * 64;
    const int tid = threadIdx.x;
    const int wid = tid >> 6, lane = tid & 63;
    const int ml = lane & 15, quad = lane >> 4;

    f32x4v acc[4] = {{0,0,0,0},{0,0,0,0},{0,0,0,0},{0,0,0,0}};

    for (int kc = 0; kc < QS; kc += 128) {
        __syncthreads();
#pragma unroll
        for (int it = 0; it < 4; ++it) {
            int u = tid + it * 256;          // 0..1023 units of 8 elems
            int row = u >> 4, c8 = (u & 15) * 8;
            float4 a0 = *(const float4*)(A + (size_t)(mb + row) * 512 + kc + c8);
            float4 a1 = *(const float4*)(A + (size_t)(mb + row) * 512 + kc + c8 + 4);
            uint4 pa = { pk2(a0.x, a0.y), pk2(a0.z, a0.w), pk2(a1.x, a1.y), pk2(a1.z, a1.w) };
            *(uint4*)&Als[row][c8] = pa;
            float4 w0 = *(const float4*)(W + (size_t)(nb + row) * 512 + kc + c8);
            float4 w1 = *(const float4*)(W + (size_t)(nb + row) * 512 + kc + c8 + 4);
            uint4 pw = { pk2(w0.x, w0.y), pk2(w0.z, w0.w), pk2(w1.x, w1.y), pk2(w1.z, w1.w) };
            *(uint4*)&Wls[row][c8] = pw;
        }
        __syncthreads();
#pragma unroll
        for (int s = 0; s < 4; ++s) {
            int k = s * 32 + quad * 8;
            bf16x8 af = *(const bf16x8*)&Als[wid * 16 + ml][k];
#pragma unroll
            for (int nt = 0; nt < 4; ++nt) {
                bf16x8 bfr = *(const bf16x8*)&Wls[nt * 16 + ml][k];
                acc[nt] = __builtin_amdgcn_mfma_f32_16x16x32_bf16(af, bfr, acc[nt], 0, 0, 0);
            }
        }
    }
    __syncthreads();
    // D frags -> LDS transpose buffer Ot[n][m]
#pragma unroll
    for (int nt = 0; nt < 4; ++nt)
#pragma unroll
        for (int r = 0; r < 4; ++r)
            Ot[nt * 16 + ml][wid * 16 + quad * 4 + r] = acc[nt][r];
    __syncthreads();
    // epilogue: bias, scale, clamp, exp2; coalesced row stores of EqT[n][m]
    {
        int r0 = tid >> 2;            // n-local 0..63
        int c0 = (tid & 3) * 16;      // m-local base
        float bs = bias[nb + r0];
#pragma unroll
        for (int g = 0; g < 4; ++g) {
            float4 v = *(const float4*)&Ot[r0][c0 + g * 4];
            float4 o;
            o.x = __builtin_amdgcn_exp2f(fminf(fmaxf(scale * (v.x + bs), -30.f), 30.f));
            o.y = __builtin_amdgcn_exp2f(fminf(fmaxf(scale * (v.y + bs), -30.f), 30.f));
            o.z = __builtin_amdgcn_exp2f(fminf(fmaxf(scale * (v.z + bs), -30.f), 30.f));
            o.w = __builtin_amdgcn_exp2f(fminf(fmaxf(scale * (v.w + bs), -30.f), 30.f));
            *(float4*)(out + (size_t)(nb + r0) * 2048 + mb + c0 + g * 4) = o;
        }
    }
}

// ---------------------------------------------------------------------------
// Kernel B: scores -> P = exp2(-acc) stored as bf16 [b][q][k] (q-major for
// MFMA A-operand in av), + per-ktile row partial sums.
//   acc(q,k) = sum_h Wv2[h]/(1 + Eq[h][q]*Ek[h][k]),  h-terms paired
//   (one rcp per two h — trans pipe is the saturated quarter-rate pipe).
// Identical core to R8 (best measured structure); Wv2 computed in-kernel.
// Grid (8,8,4), 256 thr.
// ---------------------------------------------------------------------------
__global__ __launch_bounds__(256) void score_kernel(
    const float* __restrict__ wvp, char* __restrict__ ws)
{
    const float* EqT = (const float*)(ws + OFF_EQT);   // [256][2048]
    const float* EkT = (const float*)(ws + OFF_EKT);
    unsigned short* Pq = (unsigned short*)(ws + OFF_PQ);  // [4][512][512] bf16
    float* rowpart = (float*)(ws + OFF_ROW);              // [8][2048]

    __shared__ float Qs[64][64];
    __shared__ float Ks[64][64];
    __shared__ float Wv2[H];
    __shared__ float redS[4][64];

    const int b  = blockIdx.z;
    const int qb = blockIdx.x * 64;
    const int kt = blockIdx.y;
    const int kb = kt * 64;
    const int tid = threadIdx.x;
    const int tx = tid & 15;       // q frag: tx*4 + i
    const int ty = tid >> 4;       // k frag: ty*4 + j
    const int w  = tid >> 6;
    const int lane = tid & 63;

    Wv2[tid] = wvp[tid] * (2.0f * LOG2E);   // blockDim == H == 256

    const int mq = b * LQ + qb;
    const int mk = b * LK + kb;
    const int sh = tid >> 4;
    const int sm = (tid & 15) * 4;

    float acc[4][4] = {};

    for (int h0 = 0; h0 < H; h0 += 64) {
        __syncthreads();
#pragma unroll
        for (int it = 0; it < 4; ++it) {
            int h = sh + 16 * it;
            *(float4*)&Qs[h][sm] = *(const float4*)(EqT + (size_t)(h0 + h) * M + mq + sm);
            *(float4*)&Ks[h][sm] = *(const float4*)(EkT + (size_t)(h0 + h) * M + mk + sm);
        }
        __syncthreads();
#pragma unroll 4
        for (int hh = 0; hh < 64; hh += 2) {
            float4 q1 = *(const float4*)&Qs[hh][tx * 4];
            float4 q2 = *(const float4*)&Qs[hh + 1][tx * 4];
            float4 k1 = *(const float4*)&Ks[hh][ty * 4];
            float4 k2 = *(const float4*)&Ks[hh + 1][ty * 4];
            float w1 = Wv2[h0 + hh];
            float w2 = Wv2[h0 + hh + 1];
            const float q1a[4] = {q1.x, q1.y, q1.z, q1.w};
            const float q2a[4] = {q2.x, q2.y, q2.z, q2.w};
            const float k1a[4] = {k1.x, k1.y, k1.z, k1.w};
            const float k2a[4] = {k2.x, k2.y, k2.z, k2.w};
#pragma unroll
            for (int i = 0; i < 4; ++i)
#pragma unroll
                for (int j = 0; j < 4; ++j) {
                    float ta = fmaf(q1a[i], k1a[j], 1.0f);
                    float tb = fmaf(q2a[i], k2a[j], 1.0f);
                    float num = fmaf(w1, tb, w2 * ta);
                    acc[i][j] = fmaf(num, __builtin_amdgcn_rcpf(ta * tb), acc[i][j]);
                }
        }
    }

    // Epilogue: P = exp2(-acc) -> bf16 Pq[b][q][k]; row partials per q.
    float ps[4];
#pragma unroll
    for (int i = 0; i < 4; ++i) {
        int q = qb + tx * 4 + i;
        float p0 = __builtin_amdgcn_exp2f(-acc[i][0]);
        float p1 = __builtin_amdgcn_exp2f(-acc[i][1]);
        float p2 = __builtin_amdgcn_exp2f(-acc[i][2]);
        float p3 = __builtin_amdgcn_exp2f(-acc[i][3]);
        ps[i] = (p0 + p1) + (p2 + p3);
        uint2 o = { pk2(p0, p1), pk2(p2, p3) };
        *(uint2*)(Pq + ((size_t)(b * 512 + q) * 512 + kb + ty * 4)) = o;
    }
#pragma unroll
    for (int i = 0; i < 4; ++i) {
        ps[i] += __shfl_xor(ps[i], 16, 64);
        ps[i] += __shfl_xor(ps[i], 32, 64);
    }
    if (lane < 16) {
#pragma unroll
        for (int i = 0; i < 4; ++i) redS[w][tx * 4 + i] = ps[i];
    }
    __syncthreads();
    if (tid < 64) {
        float s = (redS[0][tid] + redS[1][tid]) + (redS[2][tid] + redS[3][tid]);
        rowpart[(size_t)kt * 2048 + b * 512 + qb + tid] = s;
    }
}

// ---------------------------------------------------------------------------
// Kernel C: out = (P @ V) / rowsum via bf16 MFMA.
// A = Pq[q][k] bf16 (q-major, contiguous a-frags); B = V transposed+cast to
// bf16 [n][k] in LDS during staging (2B scatter writes, once per chunk).
// 64q x 64n tile, K-chunks 128, wave owns q-strip w*16. Grid (8,8,4).
// D store: 4 q-rows x 16 n = 4 full 64B lines per instr (coalesced).
// ---------------------------------------------------------------------------
__global__ __launch_bounds__(256) void av_mfma(
    const float* __restrict__ V, const char* __restrict__ wsc,
    float* __restrict__ O)
{
    const unsigned short* Pq = (const unsigned short*)(wsc + OFF_PQ);
    const float* rowpart = (const float*)(wsc + OFF_ROW);

    __shared__ unsigned short Pls[64][136];
    __shared__ unsigned short Vls[64][136];

    const int b = blockIdx.z, qb = blockIdx.x * 64, nb = blockIdx.y * 64;
    const int tid = threadIdx.x;
    const int wid = tid >> 6, lane = tid & 63;
    const int ml = lane & 15, quad = lane >> 4;
    const unsigned short* Pb = Pq + (size_t)b * 512 * 512;
    const float* Vb = V + (size_t)b * 512 * 512;

    f32x4v acc[4] = {{0,0,0,0},{0,0,0,0},{0,0,0,0},{0,0,0,0}};

    for (int kc = 0; kc < LK; kc += 128) {
        __syncthreads();
        // P rows: straight bf16 copy, 16B units
#pragma unroll
        for (int it = 0; it < 4; ++it) {
            int u = tid + it * 256;
            int row = u >> 4, c8 = (u & 15) * 8;
            *(uint4*)&Pls[row][c8] = *(const uint4*)(Pb + (size_t)(qb + row) * 512 + kc + c8);
        }
        // V transpose+cast: read [k][n] fp32 rows, write [n][k] bf16
#pragma unroll
        for (int it = 0; it < 8; ++it) {
            int u = tid + it * 256;           // 2048 float4 units
            int k = u >> 4, c4 = (u & 15) * 4;
            float4 v4 = *(const float4*)(Vb + (size_t)(kc + k) * 512 + nb + c4);
            Vls[c4 + 0][k] = f2bf(v4.x);
            Vls[c4 + 1][k] = f2bf(v4.y);
            Vls[c4 + 2][k] = f2bf(v4.z);
            Vls[c4 + 3][k] = f2bf(v4.w);
        }
        __syncthreads();
#pragma unroll
        for (int s = 0; s < 4; ++s) {
            int k = s * 32 + quad * 8;
            bf16x8 af = *(const bf16x8*)&Pls[wid * 16 + ml][k];
#pragma unroll
            for (int nt = 0; nt < 4; ++nt) {
                bf16x8 bfr = *(const bf16x8*)&Vls[nt * 16 + ml][k];
                acc[nt] = __builtin_amdgcn_mfma_f32_16x16x32_bf16(af, bfr, acc[nt], 0, 0, 0);
            }
        }
    }

    // epilogue: rowsum normalize + store
    float rr[4];
#pragma unroll
    for (int r = 0; r < 4; ++r) {
        int q = qb + wid * 16 + quad * 4 + r;
        float rs = 0.f;
#pragma unroll
        for (int t = 0; t < 8; ++t) rs += rowpart[(size_t)t * 2048 + b * 512 + q];
        rr[r] = 1.0f / rs;
    }
#pragma unroll
    for (int nt = 0; nt < 4; ++nt)
#pragma unroll
        for (int r = 0; r < 4; ++r) {
            int q = qb + wid * 16 + quad * 4 + r;
            O[((size_t)b * 512 + q) * 512 + nb + nt * 16 + ml] = acc[nt][r] * rr[r];
        }
}

extern "C" void kernel_launch(void* const* d_in, const int* in_sizes, int n_in,
                              void* d_out, int out_size, void* d_ws, size_t ws_size,
                              hipStream_t stream) {
    const float* query = (const float*)d_in[0];
    const float* key   = (const float*)d_in[1];
    const float* value = (const float*)d_in[2];
    const float* wq    = (const float*)d_in[3];
    const float* bq    = (const float*)d_in[4];
    const float* wk    = (const float*)d_in[5];
    const float* bk    = (const float*)d_in[6];
    const float* wv    = (const float*)d_in[7];
    // d_in[8] = bv: row-constant -> softmax-invariant, dropped.
    float* out = (float*)d_out;
    char* ws = (char*)d_ws;

    const float c2 = 2.0f * LOG2E;

    proj_mfma<<<dim3(32, 4, 2), 256, 0, stream>>>(query, key, wq, wk, bq, bk, ws, c2);
    score_kernel<<<dim3(8, 8, Bb), 256, 0, stream>>>(wv, ws);
    av_mfma<<<dim3(8, 8, Bb), 256, 0, stream>>>(value, ws, out);
}

// Round 10
// 139.509 us; speedup vs baseline: 1.8457x; 1.0059x over previous
//
#include <hip/hip_runtime.h>

#define LOG2E 1.4426950408889634f

// Problem constants
constexpr int Bb = 4, LQ = 512, LK = 512, QS = 512, H = 256, DV = 512;
constexpr int M = 2048;   // B*LQ

// Workspace byte offsets
constexpr size_t OFF_EQT = 0;            // [256][2048] f32 (2 MiB) exp2-domain q proj
constexpr size_t OFF_EKT = 2u << 20;     // [256][2048] f32 (2 MiB)
constexpr size_t OFF_PQ  = 4u << 20;     // [4][512][512] bf16 (2 MiB) P numerators
constexpr size_t OFF_ROW = 6u << 20;     // [8][2048] f32 rowsum partials

using bf16x8 = __attribute__((ext_vector_type(8))) short;
using f32x4v = __attribute__((ext_vector_type(4))) float;

__device__ inline unsigned short f2bf(float x) {
    unsigned int u = __float_as_uint(x);
    u += 0x7FFFu + ((u >> 16) & 1u);      // round-to-nearest-even
    return (unsigned short)(u >> 16);
}
__device__ inline unsigned int pk2(float lo, float hi) {
    return (unsigned int)f2bf(lo) | ((unsigned int)f2bf(hi) << 16);
}

// ---------------------------------------------------------------------------
// Kernel A: proj via bf16 MFMA + exp2 epilogue, transposed fp32 output.
//   EqT[n][m] = exp2( clamp( scale*(A[m]·W[n] + bias[n]), ±30 ) )
// (unchanged from R9 — measured fast)
// ---------------------------------------------------------------------------
__global__ __launch_bounds__(256) void proj_mfma(
    const float* __restrict__ query, const float* __restrict__ key,
    const float* __restrict__ wq, const float* __restrict__ wk,
    const float* __restrict__ bq, const float* __restrict__ bk,
    char* __restrict__ ws, float scale)
{
    const int z = blockIdx.z;
    const float* A    = z ? key : query;   // [2048][512]
    const float* W    = z ? wk : wq;       // [256][512]
    const float* bias = z ? bk : bq;
    float* out = (float*)(ws + (z ? OFF_EKT : OFF_EQT));   // [256][2048]

    __shared__ unsigned short Als[64][136];
    __shared__ unsigned short Wls[64][136];
    __shared__ float Ot[64][68];

    const int mb = blockIdx.x * 64, nb = blockIdx.y * 64;
    const int tid = threadIdx.x;
    const int wid = tid >> 6, lane = tid & 63;
    const int ml = lane & 15, quad = lane >> 4;

    f32x4v acc[4] = {{0,0,0,0},{0,0,0,0},{0,0,0,0},{0,0,0,0}};

    for (int kc = 0; kc < QS; kc += 128) {
        __syncthreads();
#pragma unroll
        for (int it = 0; it < 4; ++it) {
            int u = tid + it * 256;          // 0..1023 units of 8 elems
            int row = u >> 4, c8 = (u & 15) * 8;
            float4 a0 = *(const float4*)(A + (size_t)(mb + row) * 512 + kc + c8);
            float4 a1 = *(const float4*)(A + (size_t)(mb + row) * 512 + kc + c8 + 4);
            uint4 pa = { pk2(a0.x, a0.y), pk2(a0.z, a0.w), pk2(a1.x, a1.y), pk2(a1.z, a1.w) };
            *(uint4*)&Als[row][c8] = pa;
            float4 w0 = *(const float4*)(W + (size_t)(nb + row) * 512 + kc + c8);
            float4 w1 = *(const float4*)(W + (size_t)(nb + row) * 512 + kc + c8 + 4);
            uint4 pw = { pk2(w0.x, w0.y), pk2(w0.z, w0.w), pk2(w1.x, w1.y), pk2(w1.z, w1.w) };
            *(uint4*)&Wls[row][c8] = pw;
        }
        __syncthreads();
#pragma unroll
        for (int s = 0; s < 4; ++s) {
            int k = s * 32 + quad * 8;
            bf16x8 af = *(const bf16x8*)&Als[wid * 16 + ml][k];
#pragma unroll
            for (int nt = 0; nt < 4; ++nt) {
                bf16x8 bfr = *(const bf16x8*)&Wls[nt * 16 + ml][k];
                acc[nt] = __builtin_amdgcn_mfma_f32_16x16x32_bf16(af, bfr, acc[nt], 0, 0, 0);
            }
        }
    }
    __syncthreads();
#pragma unroll
    for (int nt = 0; nt < 4; ++nt)
#pragma unroll
        for (int r = 0; r < 4; ++r)
            Ot[nt * 16 + ml][wid * 16 + quad * 4 + r] = acc[nt][r];
    __syncthreads();
    {
        int r0 = tid >> 2;            // n-local 0..63
        int c0 = (tid & 3) * 16;      // m-local base
        float bs = bias[nb + r0];
#pragma unroll
        for (int g = 0; g < 4; ++g) {
            float4 v = *(const float4*)&Ot[r0][c0 + g * 4];
            float4 o;
            o.x = __builtin_amdgcn_exp2f(fminf(fmaxf(scale * (v.x + bs), -30.f), 30.f));
            o.y = __builtin_amdgcn_exp2f(fminf(fmaxf(scale * (v.y + bs), -30.f), 30.f));
            o.z = __builtin_amdgcn_exp2f(fminf(fmaxf(scale * (v.z + bs), -30.f), 30.f));
            o.w = __builtin_amdgcn_exp2f(fminf(fmaxf(scale * (v.w + bs), -30.f), 30.f));
            *(float4*)(out + (size_t)(nb + r0) * 2048 + mb + c0 + g * 4) = o;
        }
    }
}

// ---------------------------------------------------------------------------
// Kernel B: scores -> P = exp2(-acc) bf16 [b][q][k] + per-ktile row partials.
//   acc(q,k) = sum_h Wv2[h]/(1 + Eq[h][q]*Ek[h][k]),  h-terms paired
//   (one rcp per two h).
// R10 change: 512-THREAD blocks (8 waves -> 2 waves/SIMD from one block,
// since the HW holds ~1 block/CU here).  Same 64q x 64k tile; per-thread
// frag 4x2.  VALU and trans pipes overlap across the 2 waves/SIMD.
// Grid (8,8,4) = 256 blocks.
// ---------------------------------------------------------------------------
__global__ __launch_bounds__(512) void score_kernel(
    const float* __restrict__ wvp, char* __restrict__ ws)
{
    const float* EqT = (const float*)(ws + OFF_EQT);   // [256][2048]
    const float* EkT = (const float*)(ws + OFF_EKT);
    unsigned short* Pq = (unsigned short*)(ws + OFF_PQ);  // [4][512][512] bf16
    float* rowpart = (float*)(ws + OFF_ROW);              // [8][2048]

    __shared__ float Qs[64][64];
    __shared__ float Ks[64][64];
    __shared__ float Wv2[H];
    __shared__ float redS[32][64];

    const int b  = blockIdx.z;
    const int qb = blockIdx.x * 64;
    const int kt = blockIdx.y;
    const int kb = kt * 64;
    const int tid = threadIdx.x;
    const int tx = tid & 15;       // q frag: tx*4 + i
    const int ty = tid >> 4;       // k pair: ty*2 + j, ty 0..31

    if (tid < H) Wv2[tid] = wvp[tid] * (2.0f * LOG2E);

    const int mq = b * LQ + qb;
    const int mk = b * LK + kb;
    const int sh = tid >> 4;       // staging row 0..31 (+32)
    const int sm = (tid & 15) * 4;

    float acc[4][2] = {};

    for (int h0 = 0; h0 < H; h0 += 64) {
        __syncthreads();
#pragma unroll
        for (int it = 0; it < 2; ++it) {
            int h = sh + 32 * it;
            *(float4*)&Qs[h][sm] = *(const float4*)(EqT + (size_t)(h0 + h) * M + mq + sm);
            *(float4*)&Ks[h][sm] = *(const float4*)(EkT + (size_t)(h0 + h) * M + mk + sm);
        }
        __syncthreads();
#pragma unroll 8
        for (int hh = 0; hh < 64; hh += 2) {
            float4 q1 = *(const float4*)&Qs[hh][tx * 4];
            float4 q2 = *(const float4*)&Qs[hh + 1][tx * 4];
            float2 k1 = *(const float2*)&Ks[hh][ty * 2];
            float2 k2 = *(const float2*)&Ks[hh + 1][ty * 2];
            float w1 = Wv2[h0 + hh];
            float w2 = Wv2[h0 + hh + 1];
            const float q1a[4] = {q1.x, q1.y, q1.z, q1.w};
            const float q2a[4] = {q2.x, q2.y, q2.z, q2.w};
            const float k1a[2] = {k1.x, k1.y};
            const float k2a[2] = {k2.x, k2.y};
#pragma unroll
            for (int i = 0; i < 4; ++i)
#pragma unroll
                for (int j = 0; j < 2; ++j) {
                    float ta = fmaf(q1a[i], k1a[j], 1.0f);
                    float tb = fmaf(q2a[i], k2a[j], 1.0f);
                    float num = fmaf(w1, tb, w2 * ta);
                    acc[i][j] = fmaf(num, __builtin_amdgcn_rcpf(ta * tb), acc[i][j]);
                }
        }
    }

    // Epilogue: P = exp2(-acc) -> bf16 Pq[b][q][kb+ty*2 ..+1]; row partials.
    float ps[4];
#pragma unroll
    for (int i = 0; i < 4; ++i) {
        int q = qb + tx * 4 + i;
        float p0 = __builtin_amdgcn_exp2f(-acc[i][0]);
        float p1 = __builtin_amdgcn_exp2f(-acc[i][1]);
        ps[i] = p0 + p1;
        *(unsigned int*)(Pq + ((size_t)(b * 512 + q) * 512 + kb + ty * 2)) = pk2(p0, p1);
    }
#pragma unroll
    for (int i = 0; i < 4; ++i) redS[ty][tx * 4 + i] = ps[i];
    __syncthreads();
    if (tid < 64) {
        float s = 0.f;
#pragma unroll
        for (int r = 0; r < 32; ++r) s += redS[r][tid];
        rowpart[(size_t)kt * 2048 + b * 512 + qb + tid] = s;
    }
}

// ---------------------------------------------------------------------------
// Kernel C: out = (P @ V) / rowsum via bf16 MFMA.  (unchanged from R9)
// ---------------------------------------------------------------------------
__global__ __launch_bounds__(256) void av_mfma(
    const float* __restrict__ V, const char* __restrict__ wsc,
    float* __restrict__ O)
{
    const unsigned short* Pq = (const unsigned short*)(wsc + OFF_PQ);
    const float* rowpart = (const float*)(wsc + OFF_ROW);

    __shared__ unsigned short Pls[64][136];
    __shared__ unsigned short Vls[64][136];

    const int b = blockIdx.z, qb = blockIdx.x * 64, nb = blockIdx.y * 64;
    const int tid = threadIdx.x;
    const int wid = tid >> 6, lane = tid & 63;
    const int ml = lane & 15, quad = lane >> 4;
    const unsigned short* Pb = Pq + (size_t)b * 512 * 512;
    const float* Vb = V + (size_t)b * 512 * 512;

    f32x4v acc[4] = {{0,0,0,0},{0,0,0,0},{0,0,0,0},{0,0,0,0}};

    for (int kc = 0; kc < LK; kc += 128) {
        __syncthreads();
#pragma unroll
        for (int it = 0; it < 4; ++it) {
            int u = tid + it * 256;
            int row = u >> 4, c8 = (u & 15) * 8;
            *(uint4*)&Pls[row][c8] = *(const uint4*)(Pb + (size_t)(qb + row) * 512 + kc + c8);
        }
#pragma unroll
        for (int it = 0; it < 8; ++it) {
            int u = tid + it * 256;           // 2048 float4 units
            int k = u >> 4, c4 = (u & 15) * 4;
            float4 v4 = *(const float4*)(Vb + (size_t)(kc + k) * 512 + nb + c4);
            Vls[c4 + 0][k] = f2bf(v4.x);
            Vls[c4 + 1][k] = f2bf(v4.y);
            Vls[c4 + 2][k] = f2bf(v4.z);
            Vls[c4 + 3][k] = f2bf(v4.w);
        }
        __syncthreads();
#pragma unroll
        for (int s = 0; s < 4; ++s) {
            int k = s * 32 + quad * 8;
            bf16x8 af = *(const bf16x8*)&Pls[wid * 16 + ml][k];
#pragma unroll
            for (int nt = 0; nt < 4; ++nt) {
                bf16x8 bfr = *(const bf16x8*)&Vls[nt * 16 + ml][k];
                acc[nt] = __builtin_amdgcn_mfma_f32_16x16x32_bf16(af, bfr, acc[nt], 0, 0, 0);
            }
        }
    }

    float rr[4];
#pragma unroll
    for (int r = 0; r < 4; ++r) {
        int q = qb + wid * 16 + quad * 4 + r;
        float rs = 0.f;
#pragma unroll
        for (int t = 0; t < 8; ++t) rs += rowpart[(size_t)t * 2048 + b * 512 + q];
        rr[r] = 1.0f / rs;
    }
#pragma unroll
    for (int nt = 0; nt < 4; ++nt)
#pragma unroll
        for (int r = 0; r < 4; ++r) {
            int q = qb + wid * 16 + quad * 4 + r;
            O[((size_t)b * 512 + q) * 512 + nb + nt * 16 + ml] = acc[nt][r] * rr[r];
        }
}

extern "C" void kernel_launch(void* const* d_in, const int* in_sizes, int n_in,
                              void* d_out, int out_size, void* d_ws, size_t ws_size,
                              hipStream_t stream) {
    const float* query = (const float*)d_in[0];
    const float* key   = (const float*)d_in[1];
    const float* value = (const float*)d_in[2];
    const float* wq    = (const float*)d_in[3];
    const float* bq    = (const float*)d_in[4];
    const float* wk    = (const float*)d_in[5];
    const float* bk    = (const float*)d_in[6];
    const float* wv    = (const float*)d_in[7];
    // d_in[8] = bv: row-constant -> softmax-invariant, dropped.
    float* out = (float*)d_out;
    char* ws = (char*)d_ws;

    const float c2 = 2.0f * LOG2E;

    proj_mfma<<<dim3(32, 4, 2), 256, 0, stream>>>(query, key, wq, wk, bq, bk, ws, c2);
    score_kernel<<<dim3(8, 8, Bb), 512, 0, stream>>>(wv, ws);
    av_mfma<<<dim3(8, 8, Bb), 256, 0, stream>>>(value, ws, out);
}